// Round 18
// baseline (672.217 us; speedup 1.0000x reference)
//
#include <hip/hip_runtime.h>
#include <cstdint>
#include <cstddef>

typedef _Float16 half_t;
typedef _Float16 half8 __attribute__((ext_vector_type(8)));
typedef float f32x4 __attribute__((ext_vector_type(4)));

constexpr int NN = 131072;    // nodes
constexpr int NE = 1048576;   // edges
constexpr int NPER = 512;

#define DEVINL __device__ __forceinline__

DEVINL float sigm_(float x){ float e = __expf(-x); return __builtin_amdgcn_rcpf(1.f+e); }
DEVINL float tanh_(float x){
  x = fminf(15.f, fmaxf(-15.f, x));
  float e = __expf(-2.f*x);
  return (1.f-e)*__builtin_amdgcn_rcpf(1.f+e);
}
// byte-packed degree counters: 4 dsts per 32-bit word (max degree << 256)
DEVINL int degof(const unsigned* d32, int n){
  return (int)((d32[n>>2] >> ((n&3)*8)) & 255u);
}

// LDS-only barrier: no vmcnt drain (keeps global loads/stores in flight)
#define LDS_BARRIER() asm volatile("s_waitcnt lgkmcnt(0)\ns_barrier" ::: "memory")

// ---------------- merged prologue: weight prep + cc + embed + deg atomics ----------------
// blocks 0..1074: pack/transpose (bias fold inline). 1075..1077: cc consts.
// 1078..5173: node embed (vectorized, one 16B store/thread).
// 5174..9269: deg count, byte-packed atomics (4 counters/word -> 4x fewer lines).
__global__ void prologue_all(const float* __restrict__ wih_f, const float* __restrict__ wih_b,
                          const float* __restrict__ head_W1, const float* __restrict__ gat_W,
                          const float* __restrict__ bih_f, const float* __restrict__ bih_b,
                          const float* __restrict__ bhh_f, const float* __restrict__ bhh_b,
                          const float* __restrict__ whh_f, const float* __restrict__ whh_b,
                          half_t* __restrict__ BcombT, half_t* __restrict__ W1T,
                          half_t* __restrict__ BTgat, float* __restrict__ bias_comb,
                          half_t* __restrict__ whh16,
                          const float* __restrict__ gatWe, const float* __restrict__ attE,
                          const float* __restrict__ eW, const float* __restrict__ eb,
                          float* __restrict__ cc,
                          const float* __restrict__ x,
                          const float* __restrict__ nW, const float* __restrict__ nb,
                          half_t* __restrict__ h,
                          const int* __restrict__ ei,
                          unsigned* __restrict__ deg32, int* __restrict__ tmp){
  const int b = blockIdx.x;
  if (b >= 5174){
    // ---- deg count: byte-packed atomic rank ----
    int e = (b-5174)*256 + threadIdx.x;
    int dt = ei[NE+e];
    unsigned sh = (unsigned)(dt&3)*8u;
    unsigned old = atomicAdd(&deg32[dt>>2], 1u<<sh);
    tmp[e] = (int)((old>>sh)&255u);
    return;
  }
  if (b >= 1078){
    // ---- node embed: thread computes 8 j's of one node ----
    int gid = (b-1078)*256 + threadIdx.x;
    int n = gid>>3, j0 = (gid&7)*8;
    float x0 = x[2*n], x1 = x[2*n+1];
    half8 hv;
    #pragma unroll
    for (int u=0;u<8;u++){
      int j = j0+u;
      hv[u] = (half_t)(x0*nW[j] + x1*nW[64+j] + nb[j]);
    }
    *(half8*)(h + (size_t)n*64 + j0) = hv;
    return;
  }
  if (b >= 1075){
    // ---- cc consts ----
    int l = b - 1075, k = threadIdx.x;
    if (k < 64){
      const float* Wel = gatWe + l*4096;
      float s3=0.f;
      for (int j=0;j<64;j++) s3 += Wel[k*64+j]*attE[l*64+j];
      float c0 = eW[k]*s3, c1 = eW[64+k]*s3, cb = eb[k]*s3;
      for (int off=1; off<64; off<<=1){
        c0 += __shfl_xor(c0,off); c1 += __shfl_xor(c1,off); cb += __shfl_xor(cb,off);
      }
      if (k==0){ cc[l]=c0; cc[3+l]=c1; cc[6+l]=cb; }
    }
    return;
  }
  int gid = b*256 + threadIdx.x;
  if (gid < 147456){                       // BcombT: j<384 from wih_f else wih_b, k-contig
    int j = gid/192, k = gid%192;
    float v = (j<384)? wih_f[j*192+k] : wih_b[(j-384)*192+k];
    BcombT[gid] = (half_t)v;
  } else if (gid < 163840){                // W1T[n][k] = head_W1[k][n]
    int i = gid - 147456;
    int n = i>>8, k = i&255;
    W1T[i] = (half_t)head_W1[k*64+n];
  } else if (gid < 176128){                // BTgat[l][n][k] = gat_W[l][k][n]
    int i = gid - 163840;
    int l = i>>12, r = i&4095;
    int n = r>>6, k = r&63;
    BTgat[i] = (half_t)gat_W[l*4096 + k*64 + n];
  } else if (gid < 176896){
    int i = gid - 176128;                  // 0..767: bih with bhh r,z folded inline
    float v;
    if (i < 256)       v = bih_f[i]     + bhh_f[i];
    else if (i < 384)  v = bih_f[i];
    else if (i < 640)  v = bih_b[i-384] + bhh_b[i-384];
    else               v = bih_b[i-384];
    bias_comb[i] = v;
  } else if (gid < 275200){                // whh16: flat copy f then b (49152 each)
    int i = gid - 176896;
    float v = (i<49152)? whh_f[i] : whh_b[i-49152];
    whh16[i] = (half_t)v;
  }
}

__global__ __launch_bounds__(256) void scan1(const unsigned* __restrict__ deg32, int* __restrict__ rowstart,
                      int* __restrict__ bsum){
  __shared__ int sc[256];
  int b=blockIdx.x, t=threadIdx.x, i=b*256+t;
  int v=degof(deg32,i); sc[t]=v; __syncthreads();
  for (int off=1; off<256; off<<=1){
    int tv = (t>=off)? sc[t-off] : 0;
    __syncthreads(); sc[t]+=tv; __syncthreads();
  }
  rowstart[i]=sc[t]-v;
  if (t==255) bsum[b]=sc[255];
}
__global__ void scan2(int* __restrict__ bsum){   // 1 block x 512
  __shared__ int sc[512];
  int t=threadIdx.x; int v=bsum[t]; sc[t]=v; __syncthreads();
  for (int off=1; off<512; off<<=1){
    int tv = (t>=off)? sc[t-off] : 0;
    __syncthreads(); sc[t]+=tv; __syncthreads();
  }
  bsum[t]=sc[t]-v;
}

// ---------------- merged scan3 + fill2 ----------------
// blocks 0..511: rows2[i] = rowstart[i] + bsum[i>>8] (finalized CSR starts).
// blocks 512..4607: fill rec; slot computed inline from pre-scan3 rowstart +
// bsum (both read-only here -> no race with rows2 writes).
__global__ __launch_bounds__(256) void scan3_fill(const int* __restrict__ rowstart,
                      const int* __restrict__ bsum, int* __restrict__ rows2,
                      const int* __restrict__ ei, const float* __restrict__ ea,
                      const int* __restrict__ tmp, int4* __restrict__ rec){
  const int b = blockIdx.x;
  if (b < 512){
    int i = b*256 + threadIdx.x;
    rows2[i] = rowstart[i] + bsum[b];
  } else {
    int e = (b-512)*256 + threadIdx.x;
    int dt = ei[NE+e];
    int slot = rowstart[dt] + bsum[dt>>8] + tmp[e];
    int4 r;
    r.x = ei[e];
    r.y = __float_as_int(ea[2*e]);
    r.z = __float_as_int(ea[2*e+1]);
    r.w = dt;
    rec[slot] = r;
  }
}

// ---------------- xp GEMM with fused attention-logit epilogue (+ optional means blocks) ----------------
__global__ __launch_bounds__(256) void gemm_xp(const half_t* __restrict__ A, int lda,
                        const half_t* __restrict__ BT,
                        const float* __restrict__ attS, const float* __restrict__ attD,
                        half_t* __restrict__ xp, float* __restrict__ a_s, float* __restrict__ a_d,
                        const unsigned* __restrict__ deg32, const int* __restrict__ rowstart,
                        const int4* __restrict__ rec, float2* __restrict__ m01){
  if (blockIdx.x >= 1024){
    int n = (blockIdx.x-1024)*256 + threadIdx.x;
    int st = rowstart[n], cnt = degof(deg32,n);
    float s0=0.f, s1=0.f;
    for (int i=0;i<cnt;i++){
      int4 r = rec[st+i];
      s0 += __int_as_float(r.y);
      s1 += __int_as_float(r.z);
    }
    float inv = 1.f/(float)max(cnt,1);
    float2 m; m.x = s0*inv; m.y = s1*inv;
    m01[n] = m;
    return;
  }
  __shared__ half_t As[128*32];
  __shared__ half_t Bs[64*32];
  const int tid = threadIdx.x, m0 = blockIdx.x*128;
  const int w = tid>>6, lane = tid&63;
  const int lm = lane&15, quad = lane>>4;
  const int wm0 = w*32;
  f32x4 acc[2][4] = {};
  for (int k0=0;k0<64;k0+=32){
    {
      const int c0 = tid*2;
      #pragma unroll
      for (int u=0;u<2;u++){
        int c=c0+u; int row=c>>2; int off=(c&3)*8;
        *(half8*)(&As[row*32+off]) = *(const half8*)(&A[(size_t)(m0+row)*lda + k0 + off]);
      }
      int c=tid; int row=c>>2; int off=(c&3)*8;
      *(half8*)(&Bs[row*32+off]) = *(const half8*)(&BT[(size_t)row*64 + k0 + off]);
    }
    __syncthreads();
    half8 af[2], bf[4];
    #pragma unroll
    for (int nt=0;nt<4;nt++) bf[nt] = *(const half8*)(&Bs[(nt*16+lm)*32 + quad*8]);
    #pragma unroll
    for (int mt=0;mt<2;mt++) af[mt] = *(const half8*)(&As[(wm0+mt*16+lm)*32 + quad*8]);
    #pragma unroll
    for (int mt=0;mt<2;mt++)
      #pragma unroll
      for (int nt=0;nt<4;nt++)
        acc[mt][nt] = __builtin_amdgcn_mfma_f32_16x16x32_f16(af[mt], bf[nt], acc[mt][nt], 0,0,0);
    __syncthreads();
  }
  float vsv[4], vdv[4];
  #pragma unroll
  for (int nt=0;nt<4;nt++){ vsv[nt]=attS[nt*16+lm]; vdv[nt]=attD[nt*16+lm]; }
  #pragma unroll
  for (int mt=0;mt<2;mt++)
   #pragma unroll
   for (int r=0;r<4;r++){
    int m = m0+wm0+mt*16+quad*4+r;
    float ps=0.f, pd=0.f;
    #pragma unroll
    for (int nt=0;nt<4;nt++){
      float v = acc[mt][nt][r];
      xp[(size_t)m*64 + nt*16+lm] = (half_t)v;
      ps += v*vsv[nt]; pd += v*vdv[nt];
    }
    ps += __shfl_xor(ps,1); ps += __shfl_xor(ps,2); ps += __shfl_xor(ps,4); ps += __shfl_xor(ps,8);
    pd += __shfl_xor(pd,1); pd += __shfl_xor(pd,2); pd += __shfl_xor(pd,4); pd += __shfl_xor(pd,8);
    if (lm==0){ a_s[m]=ps; a_d[m]=pd; }
  }
}

// ---------------- flat-edge aggregate with INLINE edge-weight computation ----------------
constexpr int SWCAP = 1536;
__global__ __launch_bounds__(512,4) void agg_lds(const int* __restrict__ rowstart, const unsigned* __restrict__ deg32,
                          const int4* __restrict__ rec,
                          const float* __restrict__ a_s, const float* __restrict__ a_d,
                          const float2* __restrict__ m01, const float* __restrict__ cc, int l,
                          const half_t* __restrict__ xp, const float* __restrict__ bias,
                          half_t* __restrict__ hjk){
  __shared__ int2  swl[SWCAP];       // 12 KB
  __shared__ float nwsf[128];        // per-dst self-loop weight
  __shared__ int   ncnt[128];        // per-dst degree
  const int tid = threadIdx.x;
  const int nbase = blockIdx.x*128;
  const half_t* __restrict__ xpg = xp + ((size_t)(nbase >> 9))*32768;  // graph slab
  const int segst = rowstart[nbase];
  const int segend = rowstart[nbase+127] + degof(deg32,nbase+127);
  const int segcnt = segend - segst;
  const int w = tid>>6, lane = tid&63;
  const float c0 = cc[l], c1 = cc[3+l], cb = cc[6+l];
  int scap = segcnt < SWCAP ? segcnt : SWCAP;
  for (int i=tid; i<scap; i+=512){
    int4 r = rec[segst+i];
    float al = a_s[r.x] + a_d[r.w]
             + __int_as_float(r.y)*c0 + __int_as_float(r.z)*c1 + cb;
    al = al>0.f? al : 0.2f*al;
    int2 o;
    o.x = (r.x & 511) | ((r.w & 127) << 16);
    o.y = __float_as_int(__expf(al));
    swl[i] = o;
  }
  if (tid < 128){
    int n = nbase + tid;
    int cnt = degof(deg32,n);
    float2 m = m01[n];
    float ael = cnt? (m.x*c0 + m.y*c1 + cb) : 0.f;
    float asl = a_s[n] + a_d[n] + ael;
    asl = asl>0.f? asl : 0.2f*asl;
    nwsf[tid] = __expf(asl);
    ncnt[tid] = cnt;
  }
  const int e0 = rowstart[nbase + w*16] - segst;
  const int e1 = (w==7) ? segcnt : (rowstart[nbase + w*16 + 16] - segst);
  __syncthreads();
  const float bv = bias[lane];
  const int nlb = nbase & 511;   // graph-local base of this 128-dst segment

  auto flush = [&](int cur, float acc, float den){
    float wv = nwsf[cur];
    float xs = (float)xpg[(size_t)(nlb + cur)*64 + lane];
    float v = (acc + wv*xs)/(den + wv) + bv;
    v = v>0.f? v : 0.01f*v;
    hjk[(size_t)(nbase + cur)*192 + l*64 + lane] = (half_t)v;
  };

  if (segcnt <= SWCAP){
    const int cnt = e1 - e0;
    if (cnt > 0){
      // depth-8 pipeline: slots hold records+rows for e..e+7 (clamped)
      int2  P[8];
      float X[8];
      #pragma unroll
      for (int i=0;i<8;i++){
        int idx = e0 + (i < cnt ? i : cnt-1);
        P[i] = swl[idx];
        X[i] = (float)xpg[(size_t)(P[i].x & 511)*64 + lane];
      }
      int cur = P[0].x >> 16;
      float acc = 0.f, den = 0.f;
      int e = e0;
      for (; e + 8 <= e1; e += 8){
        #pragma unroll
        for (int i=0;i<8;i++){
          int dl = P[i].x >> 16;
          if (dl != cur){ flush(cur, acc, den); cur = dl; acc = 0.f; den = 0.f; }
          float ww = __int_as_float(P[i].y);
          acc += ww*X[i]; den += ww;
          int nidx = e + 8 + i;
          int cidx = nidx < e1 ? nidx : e1-1;    // clamped prefetch
          P[i] = swl[cidx];
          X[i] = (float)xpg[(size_t)(P[i].x & 511)*64 + lane];
        }
      }
      int rem = e1 - e;
      #pragma unroll
      for (int i=0;i<8;i++){
        if (i < rem){
          int dl = P[i].x >> 16;
          if (dl != cur){ flush(cur, acc, den); cur = dl; acc = 0.f; den = 0.f; }
          float ww = __int_as_float(P[i].y);
          acc += ww*X[i]; den += ww;
        }
      }
      flush(cur, acc, den);
    }
    #pragma unroll
    for (int i=0;i<16;i++){                    // zero-degree dsts
      int li = w*16+i;
      if (ncnt[li]==0) flush(li, 0.f, 0.f);
    }
  } else {
    // overflow path (essentially never taken): rec read from global, weight inline
    if (e0 < e1){
      auto mkw = [&](int idx)->int2{
        int4 r = rec[segst+idx];
        float al = a_s[r.x] + a_d[r.w]
                 + __int_as_float(r.y)*c0 + __int_as_float(r.z)*c1 + cb;
        al = al>0.f? al : 0.2f*al;
        int2 o;
        o.x = (r.x & 511) | ((r.w & 127) << 16);
        o.y = __float_as_int(__expf(al));
        return o;
      };
      int2 p = mkw(e0);
      float xv = (float)xpg[(size_t)(p.x & 511)*64 + lane];
      int cur = p.x >> 16;
      float acc = 0.f, den = 0.f;
      for (int e = e0; e < e1; ++e){
        int en = (e+1 < e1) ? e+1 : e;
        int2 pn = mkw(en);
        float xvn = (float)xpg[(size_t)(pn.x & 511)*64 + lane];
        int dl = p.x >> 16;
        if (dl != cur){
          flush(cur, acc, den);
          cur = dl; acc = 0.f; den = 0.f;
        }
        float ww = __int_as_float(p.y);
        acc += ww*xv; den += ww;
        p = pn; xv = xvn;
      }
      flush(cur, acc, den);
    }
    #pragma unroll
    for (int i=0;i<16;i++){
      int li = w*16+i;
      if (ncnt[li]==0) flush(li, 0.f, 0.f);
    }
  }
}

// ---------------- head GEMM with fused MLP-2 epilogue ----------------
// mode=1: blockIdx -> edge-position blocks (pos 0-127, 384-511): ib = (b>>1)*4 + (b&1)*3
__global__ __launch_bounds__(256) void gemm_head(const half_t* __restrict__ A,
                        const half_t* __restrict__ W1T, const float* __restrict__ b1,
                        const float* __restrict__ W2, const float* __restrict__ b2,
                        float* __restrict__ out, int mode){
  __shared__ half_t As[128*32];
  __shared__ half_t Bs[64*32];
  const int ib = mode ? ((blockIdx.x>>1)*4 + (blockIdx.x&1)*3) : blockIdx.x;
  const int tid = threadIdx.x, m0 = ib*128;
  const int w = tid>>6, lane = tid&63;
  const int lm = lane&15, quad = lane>>4;
  const int wm0 = w*32;
  f32x4 acc[2][4] = {};
  for (int k0=0;k0<256;k0+=32){
    {
      const int c0 = tid*2;
      #pragma unroll
      for (int u=0;u<2;u++){
        int c=c0+u; int row=c>>2; int off=(c&3)*8;
        *(half8*)(&As[row*32+off]) = *(const half8*)(&A[(size_t)(m0+row)*256 + k0 + off]);
      }
      int c=tid; int row=c>>2; int off=(c&3)*8;
      *(half8*)(&Bs[row*32+off]) = *(const half8*)(&W1T[(size_t)row*256 + k0 + off]);
    }
    __syncthreads();
    half8 af[2], bf[4];
    #pragma unroll
    for (int nt=0;nt<4;nt++) bf[nt] = *(const half8*)(&Bs[(nt*16+lm)*32 + quad*8]);
    #pragma unroll
    for (int mt=0;mt<2;mt++) af[mt] = *(const half8*)(&As[(wm0+mt*16+lm)*32 + quad*8]);
    #pragma unroll
    for (int mt=0;mt<2;mt++)
      #pragma unroll
      for (int nt=0;nt<4;nt++)
        acc[mt][nt] = __builtin_amdgcn_mfma_f32_16x16x32_f16(af[mt], bf[nt], acc[mt][nt], 0,0,0);
    __syncthreads();
  }
  float b1v[4], w20[4], w21[4];
  #pragma unroll
  for (int nt=0;nt<4;nt++){
    int n = nt*16+lm;
    b1v[nt]=b1[n]; w20[nt]=W2[n*2]; w21[nt]=W2[n*2+1];
  }
  float b20=b2[0], b21=b2[1];
  #pragma unroll
  for (int mt=0;mt<2;mt++)
   #pragma unroll
   for (int r=0;r<4;r++){
    int m = m0+wm0+mt*16+quad*4+r;
    float p0=0.f, p1=0.f;
    #pragma unroll
    for (int nt=0;nt<4;nt++){
      float v = acc[mt][nt][r] + b1v[nt];
      v = v>0.f? v : 0.f;
      p0 += v*w20[nt]; p1 += v*w21[nt];
    }
    p0 += __shfl_xor(p0,1); p0 += __shfl_xor(p0,2); p0 += __shfl_xor(p0,4); p0 += __shfl_xor(p0,8);
    p1 += __shfl_xor(p1,1); p1 += __shfl_xor(p1,2); p1 += __shfl_xor(p1,4); p1 += __shfl_xor(p1,8);
    if (lm==0){
      out[(size_t)m*2]   = p0 + b20;
      out[(size_t)m*2+1] = p1 + b21;
    }
  }
}

// ---------------- fused GRU recurrence + next-chunk gx GEMM + (c=3) middle head blocks ----------------
__global__ __launch_bounds__(512,1) void gru_fused(
    const half_t* __restrict__ whh16, const float* __restrict__ bhh_f, const float* __restrict__ bhh_b,
    const half_t* __restrict__ gxf, const half_t* __restrict__ gxb,
    float* __restrict__ hstate, half_t* __restrict__ y, int c, int gruBlocks, int gxBlocks,
    const half_t* __restrict__ hjk, const half_t* __restrict__ BcombT, const float* __restrict__ biasc,
    half_t* __restrict__ gxf_n, half_t* __restrict__ gxb_n, int s0f, int s0b,
    const half_t* __restrict__ W1T, const float* __restrict__ hb1,
    const float* __restrict__ hW2, const float* __restrict__ hb2, float* __restrict__ out){
  __shared__ __align__(16) char SMEM[24832];   // union: GRU H(8448)+YB(16384) | GEMM As+Bs(16384)
  const int bid = blockIdx.x;
  const int tid = threadIdx.x;
  if (bid < gruBlocks){
    // ---------------- GRU path ----------------
    __builtin_amdgcn_s_setprio(1);
    auto& H  = *(half_t (*)[2][16][132])SMEM;             // 8448 B
    auto& YB = *(half_t (*)[16][4][128])(SMEM + 8448);    // 16384 B
    const int d = bid >> 6, gblk = bid & 63;              // 64 blocks/dir, 4 graphs each
    const half_t* __restrict__ gx = d ? gxb : gxf;
    const float* bhh = d ? bhh_b : bhh_f;
    const int w = tid >> 6, lane = tid & 63;
    const int l15 = lane & 15, quad = lane >> 4;
    const int unit = w*16 + l15;                          // 0..127

    half8 bf[3][4];
    float bhn = bhh[256 + unit];
    {
      const half_t* wbase = whh16 + (size_t)d*49152;
      #pragma unroll
      for (int g=0; g<3; g++){
        const half_t* wp = wbase + (size_t)(g*128 + unit)*128;
        #pragma unroll
        for (int kk=0; kk<4; kk++)
          bf[g][kk] = *(const half8*)(wp + kk*32 + quad*8);
      }
    }

    float hreg = hstate[((size_t)d*256 + gblk*4 + quad)*128 + unit];

    const int jstep = d ? -384 : 384;
    const int j0 = d ? 127 : 0;
    const int pos0 = d ? (511 - c*128) : (c*128);

    // y-dump mapping: thread -> (row r = graph*16+tloc, 16-half slice)
    const int dr  = tid >> 3;            // 0..63
    const int dg  = dr >> 4;             // graph 0..3
    const int dtl = dr & 15;             // step-in-ring 0..15
    const int dof = (tid & 7)*16;        // half offset in row

    // per-thread gate prefetch: 3 halfs/step, distance-2 double set
    long gofs = ((long)(gblk*4 + quad)*128 + j0)*384 + unit;
    half_t A0,A1,A2, B0,B1,B2;
    A0 = gx[gofs]; A1 = gx[gofs+128]; A2 = gx[gofs+256]; gofs += jstep;  // t=0
    B0 = gx[gofs]; B1 = gx[gofs+128]; B2 = gx[gofs+256]; gofs += jstep;  // t=1

    H[0][quad*4][unit] = (half_t)hreg;
    LDS_BARRIER();

    auto stepf = [&](int t, int rd, int wr2, half_t& c0, half_t& c1, half_t& c2, bool pf){
      // A fragments: only rows 0,4,8,12 nonzero -> 16 active lanes read
      half8 af[4] = {};
      if ((l15 & 3) == 0){
        #pragma unroll
        for (int kk=0; kk<4; kk++)
          af[kk] = *(const half8*)&H[rd][l15][kk*32 + quad*8];
      }
      f32x4 Pa[3] = {}, Pb[3] = {};
      #pragma unroll
      for (int g=0; g<3; g++){
        Pa[g] = __builtin_amdgcn_mfma_f32_16x16x32_f16(af[0], bf[g][0], Pa[g], 0,0,0);
        Pb[g] = __builtin_amdgcn_mfma_f32_16x16x32_f16(af[2], bf[g][2], Pb[g], 0,0,0);
        Pa[g] = __builtin_amdgcn_mfma_f32_16x16x32_f16(af[1], bf[g][1], Pa[g], 0,0,0);
        Pb[g] = __builtin_amdgcn_mfma_f32_16x16x32_f16(af[3], bf[g][3], Pb[g], 0,0,0);
      }
      float p0 = Pa[0][0] + Pb[0][0];
      float p1 = Pa[1][0] + Pb[1][0];
      float p2 = Pa[2][0] + Pb[2][0];
      float rr = sigm_((float)c0 + p0);
      float zz = sigm_((float)c1 + p1);
      float nn = tanh_((float)c2 + rr*(p2 + bhn));
      float hn = nn + zz*(hreg - nn);
      hreg = hn;
      half_t hh = (half_t)hn;
      H[wr2][quad*4][unit] = hh;
      YB[t & 15][quad][unit] = hh;                        // LDS ring, no global store
      if (pf){                                            // reload this set for t+2
        c0 = gx[gofs]; c1 = gx[gofs+128]; c2 = gx[gofs+256];
        gofs += jstep;
      }
      LDS_BARRIER();
      if ((t & 15) == 15){
        // bulk y-dump of steps t-15..t : 64 rows x 128 halfs, coalesced
        int ts = (t - 15) + dtl;
        int pos = d ? (pos0 - ts) : (pos0 + ts);
        half_t* yp = y + ((size_t)(gblk*4 + dg)*512 + pos)*256 + d*128 + dof;
        uint4 v0 = *(const uint4*)&YB[dtl][dg][dof];
        uint4 v1 = *(const uint4*)&YB[dtl][dg][dof + 8];
        *(uint4*)yp = v0;
        *(uint4*)(yp + 8) = v1;
        LDS_BARRIER();                                    // YB reads done before reuse
      }
    };

    for (int t=0; t<128; t+=2){
      stepf(t,   0, 1, A0,A1,A2, t < 126);   // even step s=t:   prefetch while s<=125
      stepf(t+1, 1, 0, B0,B1,B2, t < 126);   // odd step s=t+1:  prefetch while s<=125
    }
    __builtin_amdgcn_s_setprio(0);
    hstate[((size_t)d*256 + gblk*4 + quad)*128 + unit] = hreg;
  } else if (bid < gruBlocks + gxBlocks){
    // ---------------- gx gemm path (512 threads, 8 waves) ----------------
    half_t* As = (half_t*)SMEM;             // 128*32 halfs
    half_t* Bs = (half_t*)(SMEM + 8192);    // 128*32 halfs
    const int gb = bid - gruBlocks;
    const int bx = gb & 255, by = gb >> 8;       // 256 x 6
    const int m0 = bx*128;
    const bool back = by >= 3;
    const int n0 = (back ? by-3 : by)*128;
    const int step0 = back ? s0b : s0f;
    half_t* C = back ? gxb_n : gxf_n;
    const half_t* BTh = BcombT + (back ? (size_t)384*192 : 0);
    const float* bh = biasc + (back ? 384 : 0);
    const int w = tid>>6, lane = tid&63;
    const int lm = lane&15, quad = lane>>4;
    const int wm0 = (w>>2)*64, wn0 = (w&3)*32;
    f32x4 acc[4][2] = {};
    for (int k0=0; k0<192; k0+=32){
      {
        int cidx = tid; int row = cidx>>2; int off = (cidx&3)*8;
        int m = m0+row;
        size_t arow = (size_t)(m>>7)*512 + step0 + (m&127);
        *(half8*)(&As[row*32+off]) = *(const half8*)(&hjk[arow*192 + k0 + off]);
        *(half8*)(&Bs[row*32+off]) = *(const half8*)(&BTh[(size_t)(n0+row)*192 + k0 + off]);
      }
      __syncthreads();
      half8 af[4], bfr[2];
      #pragma unroll
      for (int nt=0;nt<2;nt++) bfr[nt] = *(const half8*)(&Bs[(wn0+nt*16+lm)*32 + quad*8]);
      #pragma unroll
      for (int mt=0;mt<4;mt++) af[mt] = *(const half8*)(&As[(wm0+mt*16+lm)*32 + quad*8]);
      #pragma unroll
      for (int mt=0;mt<4;mt++)
        #pragma unroll
        for (int nt=0;nt<2;nt++)
          acc[mt][nt] = __builtin_amdgcn_mfma_f32_16x16x32_f16(af[mt], bfr[nt], acc[mt][nt], 0,0,0);
      __syncthreads();
    }
    #pragma unroll
    for (int mt=0;mt<4;mt++)
     #pragma unroll
     for (int nt=0;nt<2;nt++)
      #pragma unroll
      for (int r=0;r<4;r++){
        int m = m0+wm0+mt*16+quad*4+r;
        int n = n0+wn0+nt*16+lm;
        float v = acc[mt][nt][r] + bh[n];
        C[(size_t)m*384 + n] = (half_t)v;
      }
  } else {
    // ---------------- head path (c=3 launch): middle-position head blocks ----------------
    half_t* As = (half_t*)SMEM;             // 128*32 halfs
    half_t* Bs = (half_t*)(SMEM + 8192);    // 64*32 halfs
    const int hb = bid - gruBlocks - gxBlocks;
    const int ib = (hb>>1)*4 + 1 + (hb&1);
    const int m0 = ib*128;
    const bool act = tid < 256;
    const int w = tid>>6, lane = tid&63;
    const int lm = lane&15, quad = lane>>4;
    const int wm0 = w*32;
    f32x4 acc[2][4] = {};
    for (int k0=0;k0<256;k0+=32){
      if (act){
        const int c0i = tid*2;
        #pragma unroll
        for (int u=0;u<2;u++){
          int cx=c0i+u; int row=cx>>2; int off=(cx&3)*8;
          *(half8*)(&As[row*32+off]) = *(const half8*)(&y[(size_t)(m0+row)*256 + k0 + off]);
        }
        int cx=tid; int row=cx>>2; int off=(cx&3)*8;
        *(half8*)(&Bs[row*32+off]) = *(const half8*)(&W1T[(size_t)row*256 + k0 + off]);
      }
      __syncthreads();
      if (act){
        half8 af[2], bf[4];
        #pragma unroll
        for (int nt=0;nt<4;nt++) bf[nt] = *(const half8*)(&Bs[(nt*16+lm)*32 + quad*8]);
        #pragma unroll
        for (int mt=0;mt<2;mt++) af[mt] = *(const half8*)(&As[(wm0+mt*16+lm)*32 + quad*8]);
        #pragma unroll
        for (int mt=0;mt<2;mt++)
          #pragma unroll
          for (int nt=0;nt<4;nt++)
            acc[mt][nt] = __builtin_amdgcn_mfma_f32_16x16x32_f16(af[mt], bf[nt], acc[mt][nt], 0,0,0);
      }
      __syncthreads();
    }
    if (act){
      float b1v[4], w20[4], w21[4];
      #pragma unroll
      for (int nt=0;nt<4;nt++){
        int n = nt*16+lm;
        b1v[nt]=hb1[n]; w20[nt]=hW2[n*2]; w21[nt]=hW2[n*2+1];
      }
      float b20=hb2[0], b21=hb2[1];
      #pragma unroll
      for (int mt=0;mt<2;mt++)
       #pragma unroll
       for (int r=0;r<4;r++){
        int m = m0+wm0+mt*16+quad*4+r;
        float p0=0.f, p1=0.f;
        #pragma unroll
        for (int nt=0;nt<4;nt++){
          float v = acc[mt][nt][r] + b1v[nt];
          v = v>0.f? v : 0.f;
          p0 += v*w20[nt]; p1 += v*w21[nt];
        }
        p0 += __shfl_xor(p0,1); p0 += __shfl_xor(p0,2); p0 += __shfl_xor(p0,4); p0 += __shfl_xor(p0,8);
        p1 += __shfl_xor(p1,1); p1 += __shfl_xor(p1,2); p1 += __shfl_xor(p1,4); p1 += __shfl_xor(p1,8);
        if (lm==0){
          out[(size_t)m*2]   = p0 + b20;
          out[(size_t)m*2+1] = p1 + b21;
        }
      }
    }
  }
}

// ---------------- launch ----------------
extern "C" void kernel_launch(void* const* d_in, const int* in_sizes, int n_in,
                              void* d_out, int out_size, void* d_ws, size_t ws_size,
                              hipStream_t stream) {
  const float* x       = (const float*)d_in[0];
  const float* ea      = (const float*)d_in[1];
  const float* node_W  = (const float*)d_in[2];
  const float* node_b  = (const float*)d_in[3];
  const float* eW      = (const float*)d_in[4];
  const float* eb      = (const float*)d_in[5];
  const float* gat_W   = (const float*)d_in[6];
  const float* gat_We  = (const float*)d_in[7];
  const float* attS    = (const float*)d_in[8];
  const float* attD    = (const float*)d_in[9];
  const float* attE    = (const float*)d_in[10];
  const float* gat_b   = (const float*)d_in[11];
  const float* wih_f   = (const float*)d_in[12];
  const float* whh_f   = (const float*)d_in[13];
  const float* bih_f   = (const float*)d_in[14];
  const float* bhh_f   = (const float*)d_in[15];
  const float* wih_b   = (const float*)d_in[16];
  const float* whh_b   = (const float*)d_in[17];
  const float* bih_b   = (const float*)d_in[18];
  const float* bhh_b   = (const float*)d_in[19];
  const float* head_W1 = (const float*)d_in[20];
  const float* head_b1 = (const float*)d_in[21];
  const float* head_W2 = (const float*)d_in[22];
  const float* head_b2 = (const float*)d_in[23];
  const int*   ei      = (const int*)d_in[24];
  float* out = (float*)d_out;
  char* ws = (char*)d_ws;
  (void)in_sizes; (void)n_in; (void)out_size; (void)ws_size;

  size_t o = 0;
  auto alloc = [&](size_t bytes)->size_t{ size_t r=o; o += (bytes+255)&~(size_t)255; return r; };
  // persistent region
  size_t o_cc     = alloc(16*4);
  size_t o_biasc  = alloc(768*4);
  size_t o_BcombT = alloc((size_t)768*192*2);
  size_t o_BTgat  = alloc((size_t)3*4096*2);
  size_t o_W1T    = alloc((size_t)64*256*2);
  size_t o_whh16  = alloc((size_t)2*49152*2);
  size_t o_hstate = alloc((size_t)2*256*128*4);
  size_t shared_base = o;

  // GAT scratch inside shared region (dead before GRU phase)
  size_t o_deg    = alloc((size_t)NN);        // byte-packed counters, zeroed
  size_t zero_end = o;
  size_t o_tmp    = alloc((size_t)NE*4);
  size_t o_rows   = alloc((size_t)NN*4);      // pre-scan3 rowstart
  size_t o_rows2  = alloc((size_t)NN*4);      // finalized CSR starts
  size_t o_bsum   = alloc(512*4);
  size_t o_rec    = alloc((size_t)NE*16);
  size_t o_m01    = alloc((size_t)NN*8);
  size_t o_as     = alloc((size_t)NN*4);
  size_t o_ad     = alloc((size_t)NN*4);
  size_t o_h      = alloc((size_t)NN*64*2);
  size_t o_xp     = alloc((size_t)NN*64*2);
  size_t gat_end  = o;
  size_t gat_size = gat_end - shared_base;

  const size_t GXC    = (size_t)256*128*384*2;   // 25.17 MB per direction chunk
  const size_t HJK_SZ = (size_t)NN*192*2;        // 48 MB
  size_t shared_sz = gat_size > 4*GXC ? gat_size : 4*GXC;
  size_t o_gx0f = shared_base;               // aliases GAT scratch (dead by GRU phase)
  size_t o_gx0b = shared_base + GXC;
  size_t o_gx1f = shared_base + 2*GXC;
  size_t o_gx1b = shared_base + 3*GXC;
  size_t o_hjk = shared_base + shared_sz;
  size_t o_y   = o_hjk + HJK_SZ;

  unsigned* deg32 = (unsigned*)(ws+o_deg);
  int*    tmp    = (int*)(ws+o_tmp);
  int*    rows   = (int*)(ws+o_rows);
  int*    rows2  = (int*)(ws+o_rows2);
  int*    bsum   = (int*)(ws+o_bsum);
  int4*   rec    = (int4*)(ws+o_rec);
  float2* m01    = (float2*)(ws+o_m01);
  float*  a_s    = (float*)(ws+o_as);
  float*  a_d    = (float*)(ws+o_ad);
  float*  cc     = (float*)(ws+o_cc);
  float*  biasc  = (float*)(ws+o_biasc);
  half_t* h      = (half_t*)(ws+o_h);
  half_t* xp     = (half_t*)(ws+o_xp);
  half_t* hjk    = (half_t*)(ws+o_hjk);
  half_t* BcombT = (half_t*)(ws+o_BcombT);
  half_t* BTgat  = (half_t*)(ws+o_BTgat);
  half_t* W1T    = (half_t*)(ws+o_W1T);
  half_t* whh16  = (half_t*)(ws+o_whh16);
  float*  hstate = (float*)(ws+o_hstate);
  half_t* gxbuf[2][2] = {{(half_t*)(ws+o_gx0f), (half_t*)(ws+o_gx0b)},
                         {(half_t*)(ws+o_gx1f), (half_t*)(ws+o_gx1b)}};
  half_t* y      = (half_t*)(ws+o_y);

  hipMemsetAsync(ws+shared_base, 0, zero_end-shared_base, stream);   // deg32
  hipMemsetAsync(ws+o_hstate, 0, (size_t)2*256*128*4, stream);       // GRU h init

  prologue_all<<<9270,256,0,stream>>>(wih_f, wih_b, head_W1, gat_W, bih_f, bih_b, bhh_f, bhh_b,
                                   whh_f, whh_b,
                                   BcombT, W1T, BTgat, biasc, whh16,
                                   gat_We, attE, eW, eb, cc,
                                   x, node_W, node_b, h, ei, deg32, tmp);
  scan1<<<512,256,0,stream>>>(deg32, rows, bsum);
  scan2<<<1,512,0,stream>>>(bsum);
  scan3_fill<<<4608,256,0,stream>>>(rows, bsum, rows2, ei, ea, tmp, rec);

  for (int l=0;l<3;l++){
    const half_t* in = (l==0)? h : (hjk + (size_t)(l-1)*64);
    int lda = (l==0)? 64 : 192;
    int grid = (l==0)? 1536 : 1024;          // l=0 carries the 512 means blocks
    gemm_xp<<<grid,256,0,stream>>>(in, lda, BTgat + (size_t)l*4096, attS + l*64, attD + l*64,
                                   xp, a_s, a_d, deg32, rows2, rec, m01);
    agg_lds<<<1024,512,0,stream>>>(rows2, deg32, rec, a_s, a_d, m01, cc, l, xp, gat_b + l*64, hjk);
  }

  // GRU: chunked, next-chunk gemm fused; c=3 carries 512 middle-position head blocks.
  gru_fused<<<1536,512,0,stream>>>(whh16, bhh_f, bhh_b, gxbuf[0][0], gxbuf[0][1], hstate, y, 0, 0, 1536,
                                   hjk, BcombT, biasc, gxbuf[0][0], gxbuf[0][1], 0, 384,
                                   W1T, head_b1, head_W2, head_b2, out);
  for (int c=0;c<4;c++){
    int buf = c&1, nbuf = (c+1)&1;
    int gxB = (c<3) ? 1536 : 0;
    int grid = 128 + gxB + (c==3 ? 512 : 0);
    gru_fused<<<grid,512,0,stream>>>(whh16, bhh_f, bhh_b, gxbuf[buf][0], gxbuf[buf][1], hstate, y, c, 128, gxB,
                                     hjk, BcombT, biasc, gxbuf[nbuf][0], gxbuf[nbuf][1],
                                     (c+1)*128, (2-c)*128,
                                     W1T, head_b1, head_W2, head_b2, out);
  }

  gemm_head<<<512,256,0,stream>>>(y, W1T, head_b1, head_W2, head_b2, out, 1);
}

// Round 19
// 659.193 us; speedup vs baseline: 1.0198x; 1.0198x over previous
//
#include <hip/hip_runtime.h>
#include <cstdint>
#include <cstddef>

typedef _Float16 half_t;
typedef _Float16 half8 __attribute__((ext_vector_type(8)));
typedef float f32x4 __attribute__((ext_vector_type(4)));

constexpr int NN = 131072;    // nodes
constexpr int NE = 1048576;   // edges
constexpr int NPER = 512;

#define DEVINL __device__ __forceinline__

DEVINL float sigm_(float x){ float e = __expf(-x); return __builtin_amdgcn_rcpf(1.f+e); }
DEVINL float tanh_(float x){
  x = fminf(15.f, fmaxf(-15.f, x));
  float e = __expf(-2.f*x);
  return (1.f-e)*__builtin_amdgcn_rcpf(1.f+e);
}

// LDS-only barrier: no vmcnt drain (keeps global loads/stores in flight)
#define LDS_BARRIER() asm volatile("s_waitcnt lgkmcnt(0)\ns_barrier" ::: "memory")

// ---------------- merged weight prep: pack/transpose + bias fold + cc consts ----------------
__global__ void prep_pack(const float* __restrict__ wih_f, const float* __restrict__ wih_b,
                          const float* __restrict__ head_W1, const float* __restrict__ gat_W,
                          const float* __restrict__ bih_f, const float* __restrict__ bih_b,
                          const float* __restrict__ bhh_f, const float* __restrict__ bhh_b,
                          const float* __restrict__ whh_f, const float* __restrict__ whh_b,
                          half_t* __restrict__ BcombT, half_t* __restrict__ W1T,
                          half_t* __restrict__ BTgat, float* __restrict__ bias_comb,
                          half_t* __restrict__ whh16,
                          const float* __restrict__ gatWe, const float* __restrict__ attE,
                          const float* __restrict__ eW, const float* __restrict__ eb,
                          float* __restrict__ cc){
  const int b = blockIdx.x;
  if (b >= 1075){
    // ---- const_kernel: cc[l], cc[3+l], cc[6+l] ----
    int l = b - 1075, k = threadIdx.x;
    if (k < 64){
      const float* Wel = gatWe + l*4096;
      float s3=0.f;
      for (int j=0;j<64;j++) s3 += Wel[k*64+j]*attE[l*64+j];
      float c0 = eW[k]*s3, c1 = eW[64+k]*s3, cb = eb[k]*s3;
      for (int off=1; off<64; off<<=1){
        c0 += __shfl_xor(c0,off); c1 += __shfl_xor(c1,off); cb += __shfl_xor(cb,off);
      }
      if (k==0){ cc[l]=c0; cc[3+l]=c1; cc[6+l]=cb; }
    }
    return;
  }
  int gid = b*256 + threadIdx.x;
  if (gid < 147456){                       // BcombT: j<384 from wih_f else wih_b, k-contig
    int j = gid/192, k = gid%192;
    float v = (j<384)? wih_f[j*192+k] : wih_b[(j-384)*192+k];
    BcombT[gid] = (half_t)v;
  } else if (gid < 163840){                // W1T[n][k] = head_W1[k][n]
    int i = gid - 147456;
    int n = i>>8, k = i&255;
    W1T[i] = (half_t)head_W1[k*64+n];
  } else if (gid < 176128){                // BTgat[l][n][k] = gat_W[l][k][n]
    int i = gid - 163840;
    int l = i>>12, r = i&4095;
    int n = r>>6, k = r&63;
    BTgat[i] = (half_t)gat_W[l*4096 + k*64 + n];
  } else if (gid < 176896){
    int i = gid - 176128;                  // 0..767: bih with bhh r,z folded inline
    float v;
    if (i < 256)       v = bih_f[i]     + bhh_f[i];
    else if (i < 384)  v = bih_f[i];
    else if (i < 640)  v = bih_b[i-384] + bhh_b[i-384];
    else               v = bih_b[i-384];
    bias_comb[i] = v;
  } else if (gid < 275200){                // whh16: flat copy f then b (49152 each)
    int i = gid - 176896;
    float v = (i<49152)? whh_f[i] : whh_b[i-49152];
    whh16[i] = (half_t)v;
  }
}

// ---------------- merged node embedding (vectorized) + degree count ----------------
__global__ __launch_bounds__(256) void embed_deg(const float* __restrict__ x,
                            const float* __restrict__ nW, const float* __restrict__ nb,
                            half_t* __restrict__ h,
                            const int* __restrict__ ei,
                            int* __restrict__ deg, int* __restrict__ tmp){
  const int b = blockIdx.x;
  if (b < 4096){
    int gid = b*256 + threadIdx.x;         // 1,048,576 threads
    int n = gid>>3, j0 = (gid&7)*8;
    float x0 = x[2*n], x1 = x[2*n+1];
    half8 hv;
    #pragma unroll
    for (int u=0;u<8;u++){
      int j = j0+u;
      hv[u] = (half_t)(x0*nW[j] + x1*nW[64+j] + nb[j]);
    }
    *(half8*)(h + (size_t)n*64 + j0) = hv;
  } else {
    int e = (b-4096)*256 + threadIdx.x;
    int dt = ei[NE+e];
    tmp[e] = atomicAdd(&deg[dt],1);
  }
}

__global__ __launch_bounds__(256) void scan1(const int* __restrict__ deg, int* __restrict__ rowstart,
                      int* __restrict__ bsum){
  __shared__ int sc[256];
  int b=blockIdx.x, t=threadIdx.x, i=b*256+t;
  int v=deg[i]; sc[t]=v; __syncthreads();
  for (int off=1; off<256; off<<=1){
    int tv = (t>=off)? sc[t-off] : 0;
    __syncthreads(); sc[t]+=tv; __syncthreads();
  }
  rowstart[i]=sc[t]-v;
  if (t==255) bsum[b]=sc[255];
}
__global__ void scan2(int* __restrict__ bsum){   // 1 block x 512
  __shared__ int sc[512];
  int t=threadIdx.x; int v=bsum[t]; sc[t]=v; __syncthreads();
  for (int off=1; off<512; off<<=1){
    int tv = (t>=off)? sc[t-off] : 0;
    __syncthreads(); sc[t]+=tv; __syncthreads();
  }
  bsum[t]=sc[t]-v;
}

// ---------------- merged scan3 + fill2 ----------------
// blocks 0..511: rows2[i] = rowstart[i] + bsum[i>>8] (finalized CSR starts).
// blocks 512..4607: fill rec; slot computed inline from pre-scan3 rowstart +
// bsum (both read-only here -> no race with rows2 writes).
__global__ __launch_bounds__(256) void scan3_fill(const int* __restrict__ rowstart,
                      const int* __restrict__ bsum, int* __restrict__ rows2,
                      const int* __restrict__ ei, const float* __restrict__ ea,
                      const int* __restrict__ tmp, int4* __restrict__ rec){
  const int b = blockIdx.x;
  if (b < 512){
    int i = b*256 + threadIdx.x;
    rows2[i] = rowstart[i] + bsum[b];
  } else {
    int e = (b-512)*256 + threadIdx.x;
    int dt = ei[NE+e];
    int slot = rowstart[dt] + bsum[dt>>8] + tmp[e];
    int4 r;
    r.x = ei[e];
    r.y = __float_as_int(ea[2*e]);
    r.z = __float_as_int(ea[2*e+1]);
    r.w = dt;
    rec[slot] = r;
  }
}

// ---------------- xp GEMM with fused attention-logit epilogue (+ optional means blocks) ----------------
__global__ __launch_bounds__(256) void gemm_xp(const half_t* __restrict__ A, int lda,
                        const half_t* __restrict__ BT,
                        const float* __restrict__ attS, const float* __restrict__ attD,
                        half_t* __restrict__ xp, float* __restrict__ a_s, float* __restrict__ a_d,
                        const int* __restrict__ deg, const int* __restrict__ rowstart,
                        const int4* __restrict__ rec, float2* __restrict__ m01){
  if (blockIdx.x >= 1024){
    int n = (blockIdx.x-1024)*256 + threadIdx.x;
    int st = rowstart[n], cnt = deg[n];
    float s0=0.f, s1=0.f;
    for (int i=0;i<cnt;i++){
      int4 r = rec[st+i];
      s0 += __int_as_float(r.y);
      s1 += __int_as_float(r.z);
    }
    float inv = 1.f/(float)max(cnt,1);
    float2 m; m.x = s0*inv; m.y = s1*inv;
    m01[n] = m;
    return;
  }
  __shared__ half_t As[128*32];
  __shared__ half_t Bs[64*32];
  const int tid = threadIdx.x, m0 = blockIdx.x*128;
  const int w = tid>>6, lane = tid&63;
  const int lm = lane&15, quad = lane>>4;
  const int wm0 = w*32;
  f32x4 acc[2][4] = {};
  for (int k0=0;k0<64;k0+=32){
    {
      const int c0 = tid*2;
      #pragma unroll
      for (int u=0;u<2;u++){
        int c=c0+u; int row=c>>2; int off=(c&3)*8;
        *(half8*)(&As[row*32+off]) = *(const half8*)(&A[(size_t)(m0+row)*lda + k0 + off]);
      }
      int c=tid; int row=c>>2; int off=(c&3)*8;
      *(half8*)(&Bs[row*32+off]) = *(const half8*)(&BT[(size_t)row*64 + k0 + off]);
    }
    __syncthreads();
    half8 af[2], bf[4];
    #pragma unroll
    for (int nt=0;nt<4;nt++) bf[nt] = *(const half8*)(&Bs[(nt*16+lm)*32 + quad*8]);
    #pragma unroll
    for (int mt=0;mt<2;mt++) af[mt] = *(const half8*)(&As[(wm0+mt*16+lm)*32 + quad*8]);
    #pragma unroll
    for (int mt=0;mt<2;mt++)
      #pragma unroll
      for (int nt=0;nt<4;nt++)
        acc[mt][nt] = __builtin_amdgcn_mfma_f32_16x16x32_f16(af[mt], bf[nt], acc[mt][nt], 0,0,0);
    __syncthreads();
  }
  float vsv[4], vdv[4];
  #pragma unroll
  for (int nt=0;nt<4;nt++){ vsv[nt]=attS[nt*16+lm]; vdv[nt]=attD[nt*16+lm]; }
  #pragma unroll
  for (int mt=0;mt<2;mt++)
   #pragma unroll
   for (int r=0;r<4;r++){
    int m = m0+wm0+mt*16+quad*4+r;
    float ps=0.f, pd=0.f;
    #pragma unroll
    for (int nt=0;nt<4;nt++){
      float v = acc[mt][nt][r];
      xp[(size_t)m*64 + nt*16+lm] = (half_t)v;
      ps += v*vsv[nt]; pd += v*vdv[nt];
    }
    ps += __shfl_xor(ps,1); ps += __shfl_xor(ps,2); ps += __shfl_xor(ps,4); ps += __shfl_xor(ps,8);
    pd += __shfl_xor(pd,1); pd += __shfl_xor(pd,2); pd += __shfl_xor(pd,4); pd += __shfl_xor(pd,8);
    if (lm==0){ a_s[m]=ps; a_d[m]=pd; }
  }
}

// ---------------- flat-edge aggregate with INLINE edge-weight computation ----------------
constexpr int SWCAP = 1536;
__global__ __launch_bounds__(512,4) void agg_lds(const int* __restrict__ rowstart, const int* __restrict__ deg,
                          const int4* __restrict__ rec,
                          const float* __restrict__ a_s, const float* __restrict__ a_d,
                          const float2* __restrict__ m01, const float* __restrict__ cc, int l,
                          const half_t* __restrict__ xp, const float* __restrict__ bias,
                          half_t* __restrict__ hjk){
  __shared__ int2  swl[SWCAP];       // 12 KB
  __shared__ float nwsf[128];        // per-dst self-loop weight
  __shared__ int   ncnt[128];        // per-dst degree
  const int tid = threadIdx.x;
  const int nbase = blockIdx.x*128;
  const half_t* __restrict__ xpg = xp + ((size_t)(nbase >> 9))*32768;  // graph slab
  const int segst = rowstart[nbase];
  const int segend = rowstart[nbase+127] + deg[nbase+127];
  const int segcnt = segend - segst;
  const int w = tid>>6, lane = tid&63;
  const float c0 = cc[l], c1 = cc[3+l], cb = cc[6+l];
  int scap = segcnt < SWCAP ? segcnt : SWCAP;
  for (int i=tid; i<scap; i+=512){
    int4 r = rec[segst+i];
    float al = a_s[r.x] + a_d[r.w]
             + __int_as_float(r.y)*c0 + __int_as_float(r.z)*c1 + cb;
    al = al>0.f? al : 0.2f*al;
    int2 o;
    o.x = (r.x & 511) | ((r.w & 127) << 16);
    o.y = __float_as_int(__expf(al));
    swl[i] = o;
  }
  if (tid < 128){
    int n = nbase + tid;
    int cnt = deg[n];
    float2 m = m01[n];
    float ael = cnt? (m.x*c0 + m.y*c1 + cb) : 0.f;
    float asl = a_s[n] + a_d[n] + ael;
    asl = asl>0.f? asl : 0.2f*asl;
    nwsf[tid] = __expf(asl);
    ncnt[tid] = cnt;
  }
  const int e0 = rowstart[nbase + w*16] - segst;
  const int e1 = (w==7) ? segcnt : (rowstart[nbase + w*16 + 16] - segst);
  __syncthreads();
  const float bv = bias[lane];
  const int nlb = nbase & 511;   // graph-local base of this 128-dst segment

  auto flush = [&](int cur, float acc, float den){
    float wv = nwsf[cur];
    float xs = (float)xpg[(size_t)(nlb + cur)*64 + lane];
    float v = (acc + wv*xs)/(den + wv) + bv;
    v = v>0.f? v : 0.01f*v;
    hjk[(size_t)(nbase + cur)*192 + l*64 + lane] = (half_t)v;
  };

  if (segcnt <= SWCAP){
    const int cnt = e1 - e0;
    if (cnt > 0){
      // depth-8 pipeline: slots hold records+rows for e..e+7 (clamped)
      int2  P[8];
      float X[8];
      #pragma unroll
      for (int i=0;i<8;i++){
        int idx = e0 + (i < cnt ? i : cnt-1);
        P[i] = swl[idx];
        X[i] = (float)xpg[(size_t)(P[i].x & 511)*64 + lane];
      }
      int cur = P[0].x >> 16;
      float acc = 0.f, den = 0.f;
      int e = e0;
      for (; e + 8 <= e1; e += 8){
        #pragma unroll
        for (int i=0;i<8;i++){
          int dl = P[i].x >> 16;
          if (dl != cur){ flush(cur, acc, den); cur = dl; acc = 0.f; den = 0.f; }
          float ww = __int_as_float(P[i].y);
          acc += ww*X[i]; den += ww;
          int nidx = e + 8 + i;
          int cidx = nidx < e1 ? nidx : e1-1;    // clamped prefetch
          P[i] = swl[cidx];
          X[i] = (float)xpg[(size_t)(P[i].x & 511)*64 + lane];
        }
      }
      int rem = e1 - e;
      #pragma unroll
      for (int i=0;i<8;i++){
        if (i < rem){
          int dl = P[i].x >> 16;
          if (dl != cur){ flush(cur, acc, den); cur = dl; acc = 0.f; den = 0.f; }
          float ww = __int_as_float(P[i].y);
          acc += ww*X[i]; den += ww;
        }
      }
      flush(cur, acc, den);
    }
    #pragma unroll
    for (int i=0;i<16;i++){                    // zero-degree dsts
      int li = w*16+i;
      if (ncnt[li]==0) flush(li, 0.f, 0.f);
    }
  } else {
    // overflow path (essentially never taken): rec read from global, weight inline
    if (e0 < e1){
      auto mkw = [&](int idx)->int2{
        int4 r = rec[segst+idx];
        float al = a_s[r.x] + a_d[r.w]
                 + __int_as_float(r.y)*c0 + __int_as_float(r.z)*c1 + cb;
        al = al>0.f? al : 0.2f*al;
        int2 o;
        o.x = (r.x & 511) | ((r.w & 127) << 16);
        o.y = __float_as_int(__expf(al));
        return o;
      };
      int2 p = mkw(e0);
      float xv = (float)xpg[(size_t)(p.x & 511)*64 + lane];
      int cur = p.x >> 16;
      float acc = 0.f, den = 0.f;
      for (int e = e0; e < e1; ++e){
        int en = (e+1 < e1) ? e+1 : e;
        int2 pn = mkw(en);
        float xvn = (float)xpg[(size_t)(pn.x & 511)*64 + lane];
        int dl = p.x >> 16;
        if (dl != cur){
          flush(cur, acc, den);
          cur = dl; acc = 0.f; den = 0.f;
        }
        float ww = __int_as_float(p.y);
        acc += ww*xv; den += ww;
        p = pn; xv = xvn;
      }
      flush(cur, acc, den);
    }
    #pragma unroll
    for (int i=0;i<16;i++){
      int li = w*16+i;
      if (ncnt[li]==0) flush(li, 0.f, 0.f);
    }
  }
}

// ---------------- head GEMM with fused MLP-2 epilogue ----------------
// mode=1: blockIdx -> edge-position blocks (pos 0-127, 384-511): ib = (b>>1)*4 + (b&1)*3
__global__ __launch_bounds__(256) void gemm_head(const half_t* __restrict__ A,
                        const half_t* __restrict__ W1T, const float* __restrict__ b1,
                        const float* __restrict__ W2, const float* __restrict__ b2,
                        float* __restrict__ out, int mode){
  __shared__ half_t As[128*32];
  __shared__ half_t Bs[64*32];
  const int ib = mode ? ((blockIdx.x>>1)*4 + (blockIdx.x&1)*3) : blockIdx.x;
  const int tid = threadIdx.x, m0 = ib*128;
  const int w = tid>>6, lane = tid&63;
  const int lm = lane&15, quad = lane>>4;
  const int wm0 = w*32;
  f32x4 acc[2][4] = {};
  for (int k0=0;k0<256;k0+=32){
    {
      const int c0 = tid*2;
      #pragma unroll
      for (int u=0;u<2;u++){
        int c=c0+u; int row=c>>2; int off=(c&3)*8;
        *(half8*)(&As[row*32+off]) = *(const half8*)(&A[(size_t)(m0+row)*256 + k0 + off]);
      }
      int c=tid; int row=c>>2; int off=(c&3)*8;
      *(half8*)(&Bs[row*32+off]) = *(const half8*)(&W1T[(size_t)row*256 + k0 + off]);
    }
    __syncthreads();
    half8 af[2], bf[4];
    #pragma unroll
    for (int nt=0;nt<4;nt++) bf[nt] = *(const half8*)(&Bs[(nt*16+lm)*32 + quad*8]);
    #pragma unroll
    for (int mt=0;mt<2;mt++) af[mt] = *(const half8*)(&As[(wm0+mt*16+lm)*32 + quad*8]);
    #pragma unroll
    for (int mt=0;mt<2;mt++)
      #pragma unroll
      for (int nt=0;nt<4;nt++)
        acc[mt][nt] = __builtin_amdgcn_mfma_f32_16x16x32_f16(af[mt], bf[nt], acc[mt][nt], 0,0,0);
    __syncthreads();
  }
  float b1v[4], w20[4], w21[4];
  #pragma unroll
  for (int nt=0;nt<4;nt++){
    int n = nt*16+lm;
    b1v[nt]=b1[n]; w20[nt]=W2[n*2]; w21[nt]=W2[n*2+1];
  }
  float b20=b2[0], b21=b2[1];
  #pragma unroll
  for (int mt=0;mt<2;mt++)
   #pragma unroll
   for (int r=0;r<4;r++){
    int m = m0+wm0+mt*16+quad*4+r;
    float p0=0.f, p1=0.f;
    #pragma unroll
    for (int nt=0;nt<4;nt++){
      float v = acc[mt][nt][r] + b1v[nt];
      v = v>0.f? v : 0.f;
      p0 += v*w20[nt]; p1 += v*w21[nt];
    }
    p0 += __shfl_xor(p0,1); p0 += __shfl_xor(p0,2); p0 += __shfl_xor(p0,4); p0 += __shfl_xor(p0,8);
    p1 += __shfl_xor(p1,1); p1 += __shfl_xor(p1,2); p1 += __shfl_xor(p1,4); p1 += __shfl_xor(p1,8);
    if (lm==0){
      out[(size_t)m*2]   = p0 + b20;
      out[(size_t)m*2+1] = p1 + b21;
    }
  }
}

// ---------------- fused GRU recurrence + next-chunk gx GEMM + (c=3) middle head blocks ----------------
__global__ __launch_bounds__(512,1) void gru_fused(
    const half_t* __restrict__ whh16, const float* __restrict__ bhh_f, const float* __restrict__ bhh_b,
    const half_t* __restrict__ gxf, const half_t* __restrict__ gxb,
    float* __restrict__ hstate, half_t* __restrict__ y, int c, int gruBlocks, int gxBlocks,
    const half_t* __restrict__ hjk, const half_t* __restrict__ BcombT, const float* __restrict__ biasc,
    half_t* __restrict__ gxf_n, half_t* __restrict__ gxb_n, int s0f, int s0b,
    const half_t* __restrict__ W1T, const float* __restrict__ hb1,
    const float* __restrict__ hW2, const float* __restrict__ hb2, float* __restrict__ out){
  __shared__ __align__(16) char SMEM[24832];   // union: GRU H(8448)+YB(16384) | GEMM As+Bs(16384)
  const int bid = blockIdx.x;
  const int tid = threadIdx.x;
  if (bid < gruBlocks){
    // ---------------- GRU path ----------------
    __builtin_amdgcn_s_setprio(1);
    auto& H  = *(half_t (*)[2][16][132])SMEM;             // 8448 B
    auto& YB = *(half_t (*)[16][4][128])(SMEM + 8448);    // 16384 B
    const int d = bid >> 6, gblk = bid & 63;              // 64 blocks/dir, 4 graphs each
    const half_t* __restrict__ gx = d ? gxb : gxf;
    const float* bhh = d ? bhh_b : bhh_f;
    const int w = tid >> 6, lane = tid & 63;
    const int l15 = lane & 15, quad = lane >> 4;
    const int unit = w*16 + l15;                          // 0..127

    half8 bf[3][4];
    float bhn = bhh[256 + unit];
    {
      const half_t* wbase = whh16 + (size_t)d*49152;
      #pragma unroll
      for (int g=0; g<3; g++){
        const half_t* wp = wbase + (size_t)(g*128 + unit)*128;
        #pragma unroll
        for (int kk=0; kk<4; kk++)
          bf[g][kk] = *(const half8*)(wp + kk*32 + quad*8);
      }
    }

    float hreg = hstate[((size_t)d*256 + gblk*4 + quad)*128 + unit];

    const int jstep = d ? -384 : 384;
    const int j0 = d ? 127 : 0;
    const int pos0 = d ? (511 - c*128) : (c*128);

    // y-dump mapping: thread -> (row r = graph*16+tloc, 16-half slice)
    const int dr  = tid >> 3;            // 0..63
    const int dg  = dr >> 4;             // graph 0..3
    const int dtl = dr & 15;             // step-in-ring 0..15
    const int dof = (tid & 7)*16;        // half offset in row

    // per-thread gate prefetch: 3 halfs/step, distance-2 double set
    long gofs = ((long)(gblk*4 + quad)*128 + j0)*384 + unit;
    half_t A0,A1,A2, B0,B1,B2;
    A0 = gx[gofs]; A1 = gx[gofs+128]; A2 = gx[gofs+256]; gofs += jstep;  // t=0
    B0 = gx[gofs]; B1 = gx[gofs+128]; B2 = gx[gofs+256]; gofs += jstep;  // t=1

    H[0][quad*4][unit] = (half_t)hreg;
    LDS_BARRIER();

    auto stepf = [&](int t, int rd, int wr2, half_t& c0, half_t& c1, half_t& c2, bool pf){
      // A fragments: only rows 0,4,8,12 nonzero -> 16 active lanes read
      half8 af[4] = {};
      if ((l15 & 3) == 0){
        #pragma unroll
        for (int kk=0; kk<4; kk++)
          af[kk] = *(const half8*)&H[rd][l15][kk*32 + quad*8];
      }
      f32x4 Pa[3] = {}, Pb[3] = {};
      #pragma unroll
      for (int g=0; g<3; g++){
        Pa[g] = __builtin_amdgcn_mfma_f32_16x16x32_f16(af[0], bf[g][0], Pa[g], 0,0,0);
        Pb[g] = __builtin_amdgcn_mfma_f32_16x16x32_f16(af[2], bf[g][2], Pb[g], 0,0,0);
        Pa[g] = __builtin_amdgcn_mfma_f32_16x16x32_f16(af[1], bf[g][1], Pa[g], 0,0,0);
        Pb[g] = __builtin_amdgcn_mfma_f32_16x16x32_f16(af[3], bf[g][3], Pb[g], 0,0,0);
      }
      float p0 = Pa[0][0] + Pb[0][0];
      float p1 = Pa[1][0] + Pb[1][0];
      float p2 = Pa[2][0] + Pb[2][0];
      float rr = sigm_((float)c0 + p0);
      float zz = sigm_((float)c1 + p1);
      float nn = tanh_((float)c2 + rr*(p2 + bhn));
      float hn = nn + zz*(hreg - nn);
      hreg = hn;
      half_t hh = (half_t)hn;
      H[wr2][quad*4][unit] = hh;
      YB[t & 15][quad][unit] = hh;                        // LDS ring, no global store
      if (pf){                                            // reload this set for t+2
        c0 = gx[gofs]; c1 = gx[gofs+128]; c2 = gx[gofs+256];
        gofs += jstep;
      }
      LDS_BARRIER();
      if ((t & 15) == 15){
        // bulk y-dump of steps t-15..t : 64 rows x 128 halfs, coalesced
        int ts = (t - 15) + dtl;
        int pos = d ? (pos0 - ts) : (pos0 + ts);
        half_t* yp = y + ((size_t)(gblk*4 + dg)*512 + pos)*256 + d*128 + dof;
        uint4 v0 = *(const uint4*)&YB[dtl][dg][dof];
        uint4 v1 = *(const uint4*)&YB[dtl][dg][dof + 8];
        *(uint4*)yp = v0;
        *(uint4*)(yp + 8) = v1;
        LDS_BARRIER();                                    // YB reads done before reuse
      }
    };

    for (int t=0; t<128; t+=2){
      stepf(t,   0, 1, A0,A1,A2, t < 126);   // even step s=t:   prefetch while s<=125
      stepf(t+1, 1, 0, B0,B1,B2, t < 126);   // odd step s=t+1:  prefetch while s<=125
    }
    __builtin_amdgcn_s_setprio(0);
    hstate[((size_t)d*256 + gblk*4 + quad)*128 + unit] = hreg;
  } else if (bid < gruBlocks + gxBlocks){
    // ---------------- gx gemm path (512 threads, 8 waves) ----------------
    half_t* As = (half_t*)SMEM;             // 128*32 halfs
    half_t* Bs = (half_t*)(SMEM + 8192);    // 128*32 halfs
    const int gb = bid - gruBlocks;
    const int bx = gb & 255, by = gb >> 8;       // 256 x 6
    const int m0 = bx*128;
    const bool back = by >= 3;
    const int n0 = (back ? by-3 : by)*128;
    const int step0 = back ? s0b : s0f;
    half_t* C = back ? gxb_n : gxf_n;
    const half_t* BTh = BcombT + (back ? (size_t)384*192 : 0);
    const float* bh = biasc + (back ? 384 : 0);
    const int w = tid>>6, lane = tid&63;
    const int lm = lane&15, quad = lane>>4;
    const int wm0 = (w>>2)*64, wn0 = (w&3)*32;
    f32x4 acc[4][2] = {};
    for (int k0=0; k0<192; k0+=32){
      {
        int cidx = tid; int row = cidx>>2; int off = (cidx&3)*8;
        int m = m0+row;
        size_t arow = (size_t)(m>>7)*512 + step0 + (m&127);
        *(half8*)(&As[row*32+off]) = *(const half8*)(&hjk[arow*192 + k0 + off]);
        *(half8*)(&Bs[row*32+off]) = *(const half8*)(&BTh[(size_t)(n0+row)*192 + k0 + off]);
      }
      __syncthreads();
      half8 af[4], bfr[2];
      #pragma unroll
      for (int nt=0;nt<2;nt++) bfr[nt] = *(const half8*)(&Bs[(wn0+nt*16+lm)*32 + quad*8]);
      #pragma unroll
      for (int mt=0;mt<4;mt++) af[mt] = *(const half8*)(&As[(wm0+mt*16+lm)*32 + quad*8]);
      #pragma unroll
      for (int mt=0;mt<4;mt++)
        #pragma unroll
        for (int nt=0;nt<2;nt++)
          acc[mt][nt] = __builtin_amdgcn_mfma_f32_16x16x32_f16(af[mt], bfr[nt], acc[mt][nt], 0,0,0);
      __syncthreads();
    }
    #pragma unroll
    for (int mt=0;mt<4;mt++)
     #pragma unroll
     for (int nt=0;nt<2;nt++)
      #pragma unroll
      for (int r=0;r<4;r++){
        int m = m0+wm0+mt*16+quad*4+r;
        int n = n0+wn0+nt*16+lm;
        float v = acc[mt][nt][r] + bh[n];
        C[(size_t)m*384 + n] = (half_t)v;
      }
  } else {
    // ---------------- head path (c=3 launch): middle-position head blocks ----------------
    half_t* As = (half_t*)SMEM;             // 128*32 halfs
    half_t* Bs = (half_t*)(SMEM + 8192);    // 64*32 halfs
    const int hb = bid - gruBlocks - gxBlocks;
    const int ib = (hb>>1)*4 + 1 + (hb&1);
    const int m0 = ib*128;
    const bool act = tid < 256;
    const int w = tid>>6, lane = tid&63;
    const int lm = lane&15, quad = lane>>4;
    const int wm0 = w*32;
    f32x4 acc[2][4] = {};
    for (int k0=0;k0<256;k0+=32){
      if (act){
        const int c0i = tid*2;
        #pragma unroll
        for (int u=0;u<2;u++){
          int cx=c0i+u; int row=cx>>2; int off=(cx&3)*8;
          *(half8*)(&As[row*32+off]) = *(const half8*)(&y[(size_t)(m0+row)*256 + k0 + off]);
        }
        int cx=tid; int row=cx>>2; int off=(cx&3)*8;
        *(half8*)(&Bs[row*32+off]) = *(const half8*)(&W1T[(size_t)row*256 + k0 + off]);
      }
      __syncthreads();
      if (act){
        half8 af[2], bf[4];
        #pragma unroll
        for (int nt=0;nt<4;nt++) bf[nt] = *(const half8*)(&Bs[(nt*16+lm)*32 + quad*8]);
        #pragma unroll
        for (int mt=0;mt<2;mt++) af[mt] = *(const half8*)(&As[(wm0+mt*16+lm)*32 + quad*8]);
        #pragma unroll
        for (int mt=0;mt<2;mt++)
          #pragma unroll
          for (int nt=0;nt<4;nt++)
            acc[mt][nt] = __builtin_amdgcn_mfma_f32_16x16x32_f16(af[mt], bf[nt], acc[mt][nt], 0,0,0);
      }
      __syncthreads();
    }
    if (act){
      float b1v[4], w20[4], w21[4];
      #pragma unroll
      for (int nt=0;nt<4;nt++){
        int n = nt*16+lm;
        b1v[nt]=hb1[n]; w20[nt]=hW2[n*2]; w21[nt]=hW2[n*2+1];
      }
      float b20=hb2[0], b21=hb2[1];
      #pragma unroll
      for (int mt=0;mt<2;mt++)
       #pragma unroll
       for (int r=0;r<4;r++){
        int m = m0+wm0+mt*16+quad*4+r;
        float p0=0.f, p1=0.f;
        #pragma unroll
        for (int nt=0;nt<4;nt++){
          float v = acc[mt][nt][r] + b1v[nt];
          v = v>0.f? v : 0.f;
          p0 += v*w20[nt]; p1 += v*w21[nt];
        }
        p0 += __shfl_xor(p0,1); p0 += __shfl_xor(p0,2); p0 += __shfl_xor(p0,4); p0 += __shfl_xor(p0,8);
        p1 += __shfl_xor(p1,1); p1 += __shfl_xor(p1,2); p1 += __shfl_xor(p1,4); p1 += __shfl_xor(p1,8);
        if (lm==0){
          out[(size_t)m*2]   = p0 + b20;
          out[(size_t)m*2+1] = p1 + b21;
        }
      }
    }
  }
}

// ---------------- launch ----------------
extern "C" void kernel_launch(void* const* d_in, const int* in_sizes, int n_in,
                              void* d_out, int out_size, void* d_ws, size_t ws_size,
                              hipStream_t stream) {
  const float* x       = (const float*)d_in[0];
  const float* ea      = (const float*)d_in[1];
  const float* node_W  = (const float*)d_in[2];
  const float* node_b  = (const float*)d_in[3];
  const float* eW      = (const float*)d_in[4];
  const float* eb      = (const float*)d_in[5];
  const float* gat_W   = (const float*)d_in[6];
  const float* gat_We  = (const float*)d_in[7];
  const float* attS    = (const float*)d_in[8];
  const float* attD    = (const float*)d_in[9];
  const float* attE    = (const float*)d_in[10];
  const float* gat_b   = (const float*)d_in[11];
  const float* wih_f   = (const float*)d_in[12];
  const float* whh_f   = (const float*)d_in[13];
  const float* bih_f   = (const float*)d_in[14];
  const float* bhh_f   = (const float*)d_in[15];
  const float* wih_b   = (const float*)d_in[16];
  const float* whh_b   = (const float*)d_in[17];
  const float* bih_b   = (const float*)d_in[18];
  const float* bhh_b   = (const float*)d_in[19];
  const float* head_W1 = (const float*)d_in[20];
  const float* head_b1 = (const float*)d_in[21];
  const float* head_W2 = (const float*)d_in[22];
  const float* head_b2 = (const float*)d_in[23];
  const int*   ei      = (const int*)d_in[24];
  float* out = (float*)d_out;
  char* ws = (char*)d_ws;
  (void)in_sizes; (void)n_in; (void)out_size; (void)ws_size;

  size_t o = 0;
  auto alloc = [&](size_t bytes)->size_t{ size_t r=o; o += (bytes+255)&~(size_t)255; return r; };
  // persistent region
  size_t o_cc     = alloc(16*4);
  size_t o_biasc  = alloc(768*4);
  size_t o_BcombT = alloc((size_t)768*192*2);
  size_t o_BTgat  = alloc((size_t)3*4096*2);
  size_t o_W1T    = alloc((size_t)64*256*2);
  size_t o_whh16  = alloc((size_t)2*49152*2);
  size_t o_hstate = alloc((size_t)2*256*128*4);
  size_t shared_base = o;

  // GAT scratch inside shared region (dead before GRU phase)
  size_t o_deg    = alloc((size_t)NN*4);      // zeroed
  size_t zero_end = o;
  size_t o_tmp    = alloc((size_t)NE*4);
  size_t o_rows   = alloc((size_t)NN*4);      // pre-scan3 rowstart
  size_t o_rows2  = alloc((size_t)NN*4);      // finalized CSR starts
  size_t o_bsum   = alloc(512*4);
  size_t o_rec    = alloc((size_t)NE*16);
  size_t o_m01    = alloc((size_t)NN*8);
  size_t o_as     = alloc((size_t)NN*4);
  size_t o_ad     = alloc((size_t)NN*4);
  size_t o_h      = alloc((size_t)NN*64*2);
  size_t o_xp     = alloc((size_t)NN*64*2);
  size_t gat_end  = o;
  size_t gat_size = gat_end - shared_base;

  const size_t GXC    = (size_t)256*128*384*2;   // 25.17 MB per direction chunk
  const size_t HJK_SZ = (size_t)NN*192*2;        // 48 MB
  size_t shared_sz = gat_size > 4*GXC ? gat_size : 4*GXC;
  size_t o_gx0f = shared_base;               // aliases GAT scratch (dead by GRU phase)
  size_t o_gx0b = shared_base + GXC;
  size_t o_gx1f = shared_base + 2*GXC;
  size_t o_gx1b = shared_base + 3*GXC;
  size_t o_hjk = shared_base + shared_sz;
  size_t o_y   = o_hjk + HJK_SZ;

  int*    deg    = (int*)(ws+o_deg);
  int*    tmp    = (int*)(ws+o_tmp);
  int*    rows   = (int*)(ws+o_rows);
  int*    rows2  = (int*)(ws+o_rows2);
  int*    bsum   = (int*)(ws+o_bsum);
  int4*   rec    = (int4*)(ws+o_rec);
  float2* m01    = (float2*)(ws+o_m01);
  float*  a_s    = (float*)(ws+o_as);
  float*  a_d    = (float*)(ws+o_ad);
  float*  cc     = (float*)(ws+o_cc);
  float*  biasc  = (float*)(ws+o_biasc);
  half_t* h      = (half_t*)(ws+o_h);
  half_t* xp     = (half_t*)(ws+o_xp);
  half_t* hjk    = (half_t*)(ws+o_hjk);
  half_t* BcombT = (half_t*)(ws+o_BcombT);
  half_t* BTgat  = (half_t*)(ws+o_BTgat);
  half_t* W1T    = (half_t*)(ws+o_W1T);
  half_t* whh16  = (half_t*)(ws+o_whh16);
  float*  hstate = (float*)(ws+o_hstate);
  half_t* gxbuf[2][2] = {{(half_t*)(ws+o_gx0f), (half_t*)(ws+o_gx0b)},
                         {(half_t*)(ws+o_gx1f), (half_t*)(ws+o_gx1b)}};
  half_t* y      = (half_t*)(ws+o_y);

  hipMemsetAsync(ws+shared_base, 0, zero_end-shared_base, stream);   // deg
  hipMemsetAsync(ws+o_hstate, 0, (size_t)2*256*128*4, stream);       // GRU h init

  prep_pack<<<1078,256,0,stream>>>(wih_f, wih_b, head_W1, gat_W, bih_f, bih_b, bhh_f, bhh_b,
                                   whh_f, whh_b,
                                   BcombT, W1T, BTgat, biasc, whh16,
                                   gat_We, attE, eW, eb, cc);
  embed_deg<<<8192,256,0,stream>>>(x, node_W, node_b, h, ei, deg, tmp);
  scan1<<<512,256,0,stream>>>(deg, rows, bsum);
  scan2<<<1,512,0,stream>>>(bsum);
  scan3_fill<<<4608,256,0,stream>>>(rows, bsum, rows2, ei, ea, tmp, rec);

  for (int l=0;l<3;l++){
    const half_t* in = (l==0)? h : (hjk + (size_t)(l-1)*64);
    int lda = (l==0)? 64 : 192;
    int grid = (l==0)? 1536 : 1024;          // l=0 carries the 512 means blocks
    gemm_xp<<<grid,256,0,stream>>>(in, lda, BTgat + (size_t)l*4096, attS + l*64, attD + l*64,
                                   xp, a_s, a_d, deg, rows2, rec, m01);
    agg_lds<<<1024,512,0,stream>>>(rows2, deg, rec, a_s, a_d, m01, cc, l, xp, gat_b + l*64, hjk);
  }

  // GRU: chunked, next-chunk gemm fused; c=3 carries 512 middle-position head blocks.
  gru_fused<<<1536,512,0,stream>>>(whh16, bhh_f, bhh_b, gxbuf[0][0], gxbuf[0][1], hstate, y, 0, 0, 1536,
                                   hjk, BcombT, biasc, gxbuf[0][0], gxbuf[0][1], 0, 384,
                                   W1T, head_b1, head_W2, head_b2, out);
  for (int c=0;c<4;c++){
    int buf = c&1, nbuf = (c+1)&1;
    int gxB = (c<3) ? 1536 : 0;
    int grid = 128 + gxB + (c==3 ? 512 : 0);
    gru_fused<<<grid,512,0,stream>>>(whh16, bhh_f, bhh_b, gxbuf[buf][0], gxbuf[buf][1], hstate, y, c, 128, gxB,
                                     hjk, BcombT, biasc, gxbuf[nbuf][0], gxbuf[nbuf][1],
                                     (c+1)*128, (2-c)*128,
                                     W1T, head_b1, head_W2, head_b2, out);
  }

  gemm_head<<<512,256,0,stream>>>(y, W1T, head_b1, head_W2, head_b2, out, 1);
}